// Round 23
// baseline (214.285 us; speedup 1.0000x reference)
//
#include <hip/hip_runtime.h>
#include <hip/hip_bf16.h>
#include <stdint.h>

// ---- problem constants ----
#define NCLS   19
#define CACHE  5000
#define NTILE  313            // 16-col tiles per class (313*16 = 5008, 8 pad cols)
#define DDIM   256
#define NANCH  102
#define NVIEW  10
#define NROWS  1020
#define NSUB   13             // column sub-chunks per class
#define NCHUNK (NCLS*NSUB)    // 247
#define NWG    (4*NCHUNK)     // 988 pass1 blocks
#define SCALE_A 20.6099319733f   // (1/0.07) * log2(e): MFMA acc = s * log2(e)
#define LN2     0.69314718056f

using f32x4 = __attribute__((ext_vector_type(4))) float;
typedef long fp8x8;   // 8 packed OCP e4m3 bytes = one i64 MFMA operand (2 VGPRs)

#if __has_builtin(__builtin_amdgcn_exp2f)
#define EXP2(x) __builtin_amdgcn_exp2f(x)
#else
#define EXP2(x) __expf((x) * LN2)
#endif

// pack 4 f32 -> 4 OCP e4m3 bytes (gfx950: cvt_pk_fp8 emits OCP, not fnuz)
static __device__ __forceinline__ unsigned cvt4(float a, float b, float c, float d) {
    int w = 0;
    w = __builtin_amdgcn_cvt_pk_fp8_f32(a, b, w, false);   // bytes 0,1
    w = __builtin_amdgcn_cvt_pk_fp8_f32(c, d, w, true);    // bytes 2,3
    return (unsigned)w;
}

// Raw barrier WITHOUT the vmcnt(0) drain __syncthreads emits (m97/m233).
#define BARRIER_NODRAIN() do {                                   \
        asm volatile("s_waitcnt lgkmcnt(0)" ::: "memory");       \
        __builtin_amdgcn_sched_barrier(0);                       \
        __builtin_amdgcn_s_barrier();                            \
        __builtin_amdgcn_sched_barrier(0);                       \
    } while (0)

// ---- anchors: view-major [1024][256] fp8, pre-scaled by (1/T)*log2(e) ----
__global__ __launch_bounds__(64) void conv_anchor_fp8(const float* __restrict__ X,
                                                      unsigned* __restrict__ A8) {
    int n = blockIdx.x;     // 0..1023
    int k = threadIdx.x;    // 0..63, handles f32 elems k*4..+3
    float v0 = 0.f, v1 = 0.f, v2 = 0.f, v3 = 0.f;
    if (n < NROWS) {
        int vv = n / NANCH, a = n - vv * NANCH;
        f32x4 u = *reinterpret_cast<const f32x4*>(
            X + ((size_t)a * NVIEW + vv) * DDIM + k * 4);
        v0 = u[0] * SCALE_A; v1 = u[1] * SCALE_A;
        v2 = u[2] * SCALE_A; v3 = u[3] * SCALE_A;
    }
    A8[(size_t)n * 64 + k] = cvt4(v0, v1, v2, v3);
}

// ---- fused pass: R22 fp8 pipeline, occupancy raised to 4 waves/SIMD ----
// True architectural live set ~100 regs (84 VGPR + ~16 AGPR, unified file)
// fits the 128-reg budget of 4 waves/SIMD — the precondition R6/R17 lacked
// (bf16's ~250-reg live set). Single variable vs R22: launch_bounds (256,4).
__global__ __launch_bounds__(256, 4) void pass1_kernel(
    const unsigned char* __restrict__ A8, const float* __restrict__ Qf,
    const int* __restrict__ y,
    float* __restrict__ Pt, float* __restrict__ Pe, float* __restrict__ Ps)
{
    __shared__ unsigned char lds[2][4096];   // 2 x 4KB fp8 fragment tiles

    // bijective XCD swizzle (m204): nwg=988, 8 XCDs, q=123, r=4.
    int orig = blockIdx.x;
    int xcd = orig & 7, slot = orig >> 3;
    int wid = (xcd < 4 ? xcd * 124 : 496 + (xcd - 4) * 123) + slot;
    int rt = wid & 3;           // row tile (256 rows)
    int cs = wid >> 2;          // 0..246 column chunk
    int cls = cs / NSUB;
    int sub = cs - cls * NSUB;
    int t0 = (NTILE * sub) / NSUB, t1 = (NTILE * (sub + 1)) / NSUB;

    int tid = threadIdx.x;
    int wave = tid >> 6, lane = tid & 63;
    int lg = lane >> 4, lm = lane & 15;
    int wrb = rt * 256 + wave * 64;   // this wave owns rows [wrb, wrb+64)

    // stage-thread mapping (R10): col c = tid>>4, 64B f32 segment seg = tid&15
    int c   = tid >> 4;
    int seg = tid & 15;
    unsigned wa0 = ((unsigned)(seg * 256 + c * 8)) ^ ((unsigned)((seg >> 1) << 4));
    const float* qbase = Qf + (size_t)cls * CACHE * DDIM + seg * 16;

    // A fragments (fp8, log2-scaled): frag f rows wrb+f*16, row = lane&15,
    // k = kk*32 + lg*8 + j  ->  8 bytes at row*256 + kk*32 + lg*8
    fp8x8 afrag[4][8];
    #pragma unroll
    for (int f = 0; f < 4; ++f)
        #pragma unroll
        for (int kk = 0; kk < 8; ++kk)
            afrag[f][kk] = *reinterpret_cast<const long*>(
                A8 + (size_t)(wrb + f * 16 + lm) * DDIM + kk * 32 + lg * 8);

    float tacc[4][4] = {}, sacc[4][4] = {};

    // two named staging reg sets (distance-2 prefetch)
    f32x4 sA0, sA1, sA2, sA3, sB0, sB1, sB2, sB3;
    bool okA, okB;

#define SLOAD1(R0, R1, R2, R3, OK, t) do {                                    \
        int _col = (t) * 16 + c;                                              \
        OK = _col < CACHE;                                                    \
        const f32x4* _src = reinterpret_cast<const f32x4*>(                   \
            qbase + (size_t)(OK ? _col : CACHE - 1) * DDIM);                  \
        R0 = _src[0]; R1 = _src[1]; R2 = _src[2]; R3 = _src[3];               \
    } while (0)

#define CVTW1(R0, R1, R2, R3, OK, buf) do {                                   \
        unsigned _w0 = cvt4(R0[0], R0[1], R0[2], R0[3]);                      \
        unsigned _w1 = cvt4(R1[0], R1[1], R1[2], R1[3]);                      \
        unsigned _w2 = cvt4(R2[0], R2[1], R2[2], R2[3]);                      \
        unsigned _w3 = cvt4(R3[0], R3[1], R3[2], R3[3]);                      \
        unsigned long long _lo = (unsigned long long)_w0 |                    \
                                 ((unsigned long long)_w1 << 32);             \
        unsigned long long _hi = (unsigned long long)_w2 |                    \
                                 ((unsigned long long)_w3 << 32);             \
        if (!OK) { _lo = 0ull; _hi = 0ull; }                                  \
        *reinterpret_cast<unsigned long long*>(&lds[buf][wa0])       = _lo;   \
        *reinterpret_cast<unsigned long long*>(&lds[buf][wa0 + 128]) = _hi;   \
    } while (0)

#define COMPUTE(buf) do {                                                     \
        fp8x8 bfrag[8];                                                       \
        _Pragma("unroll")                                                     \
        for (int kk = 0; kk < 8; ++kk)                                        \
            bfrag[kk] = *reinterpret_cast<const long*>(                       \
                &lds[buf][(unsigned)((kk * 64 + lane) * 8) ^                  \
                          (unsigned)(kk << 4)]);                              \
        f32x4 acc[4];                                                         \
        _Pragma("unroll")                                                     \
        for (int f = 0; f < 4; ++f) acc[f] = (f32x4){0.f, 0.f, 0.f, 0.f};     \
        _Pragma("unroll")                                                     \
        for (int kk = 0; kk < 8; ++kk)                                        \
            _Pragma("unroll")                                                 \
            for (int f = 0; f < 4; ++f)                                       \
                acc[f] = __builtin_amdgcn_mfma_f32_16x16x32_fp8_fp8(          \
                    afrag[f][kk], bfrag[kk], acc[f], 0, 0, 0);                \
        _Pragma("unroll")                                                     \
        for (int f = 0; f < 4; ++f)                                           \
            _Pragma("unroll")                                                 \
            for (int r = 0; r < 4; ++r) {                                     \
                float v = acc[f][r];            /* s * log2(e) */             \
                tacc[f][r] += EXP2(v);          /* pad cols: v=0 -> e=1 */    \
                sacc[f][r] += v;                                              \
            }                                                                 \
    } while (0)

#define SLOADA(t) SLOAD1(sA0, sA1, sA2, sA3, okA, t)
#define SLOADB(t) SLOAD1(sB0, sB1, sB2, sB3, okB, t)
#define CVTWRITEA(buf) CVTW1(sA0, sA1, sA2, sA3, okA, buf)
#define CVTWRITEB(buf) CVTW1(sB0, sB1, sB2, sB3, okB, buf)

    int nt = t1 - t0;

    // prologue: window 0 staged via A; window 1 preloaded into B
    SLOADA(t0);
    CVTWRITEA(0);
    if (nt > 1) SLOADB(t0 + 1);
    BARRIER_NODRAIN();

    int cur = 0, it = 0;
    for (;;) {
        if (it + 2 < nt) SLOADA(t0 + it + 2);
        COMPUTE(cur);
        if (it + 1 < nt) CVTWRITEB(cur ^ 1);
        BARRIER_NODRAIN();
        cur ^= 1; ++it;
        if (it >= nt) break;

        if (it + 2 < nt) SLOADB(t0 + it + 2);
        COMPUTE(cur);
        if (it + 1 < nt) CVTWRITEA(cur ^ 1);
        BARRIER_NODRAIN();
        cur ^= 1; ++it;
        if (it >= nt) break;
    }
#undef SLOAD1
#undef CVTW1
#undef COMPUTE
#undef SLOADA
#undef SLOADB
#undef CVTWRITEA
#undef CVTWRITEB

    // reduce across the 16 column-lanes (lm) and store per-chunk partials
    #pragma unroll
    for (int f = 0; f < 4; ++f)
        #pragma unroll
        for (int r = 0; r < 4; ++r) {
            float t = tacc[f][r], s = sacc[f][r];
            #pragma unroll
            for (int m = 1; m < 16; m <<= 1) {
                t += __shfl_xor(t, m);
                s += __shfl_xor(s, m);
            }
            if (lm == 0) {
                int row = wrb + f * 16 + lg * 4 + r;
                float mp = (row < NROWS && y[row % NANCH] == cls) ? 1.0f : 0.0f;
                size_t idx = (size_t)cs * 1024 + row;
                Pt[idx] = t; Pe[idx] = mp * t; Ps[idx] = mp * s;
            }
        }
}

// ---- per-row finalization + final mean, fused ----
__global__ __launch_bounds__(256) void reduce_rows(const float* __restrict__ Pt,
                                                   const float* __restrict__ Pe,
                                                   const float* __restrict__ Ps,
                                                   float* __restrict__ out) {
    int tid = threadIdx.x;
    int row = blockIdx.x * 64 + (tid >> 2);   // 0..1023
    int part = tid & 3;
    float tot = 0.f, pe = 0.f, ps = 0.f;
    for (int c = part; c < NCHUNK; c += 4) {
        size_t idx = (size_t)c * 1024 + row;
        tot += Pt[idx]; pe += Pe[idx]; ps += Ps[idx];
    }
    tot += __shfl_xor(tot, 1); pe += __shfl_xor(pe, 1); ps += __shfl_xor(ps, 1);
    tot += __shfl_xor(tot, 2); pe += __shfl_xor(pe, 2); ps += __shfl_xor(ps, 2);
    float contrib = 0.f;
    if (part == 0 && row < NROWS) {
        // tot includes all 19*8=152 pad cols (e=1 each); pe the 8 pads of pos class
        float ns    = tot - pe - 144.0f;        // sum exp over true negatives
        float pos_e = pe - 8.0f;                // sum exp over true positives
        float pos_s = ps * LN2;                 // sum of s over positives (ln domain)
        // sum_pos log(e^s + ns) ~= 5000*log(ns) + pos_e/ns   (first-order log1p)
        float sum_logprob = pos_s - (5000.0f * logf(ns) + pos_e / ns);
        contrib = -sum_logprob / (5000.0f + 1e-4f);
    }
    #pragma unroll
    for (int m = 1; m < 64; m <<= 1) contrib += __shfl_xor(contrib, m);
    __shared__ float sb[4];
    if ((tid & 63) == 0) sb[tid >> 6] = contrib;
    __syncthreads();
    if (tid == 0)
        atomicAdd(out, (sb[0] + sb[1] + sb[2] + sb[3]) * (1.0f / (float)NROWS));
}

extern "C" void kernel_launch(void* const* d_in, const int* in_sizes, int n_in,
                              void* d_out, int out_size, void* d_ws, size_t ws_size,
                              hipStream_t stream) {
    const float* X  = (const float*)d_in[0];   // [102][10][256]
    const int*   y  = (const int*)d_in[1];     // [102]
    const float* Qf = (const float*)d_in[2];   // [19][5000][256]
    float* out = (float*)d_out;

    char* ws = (char*)d_ws;
    // ws layout (bytes):
    //   A8  [1024][256] fp8            :    262,144
    //   Pt  [247][1024] f32            :  1,011,712
    //   Pe  [247][1024] f32            :  1,011,712
    //   Ps  [247][1024] f32            :  1,011,712
    unsigned char* A8 = (unsigned char*)(ws);
    float* Pt = (float*)(ws + 262144);
    float* Pe = (float*)(ws + 1273856);
    float* Ps = (float*)(ws + 2285568);

    hipMemsetAsync(out, 0, sizeof(float) * (size_t)out_size, stream);
    conv_anchor_fp8<<<1024, 64, 0, stream>>>(X, (unsigned*)A8);
    pass1_kernel<<<NWG, 256, 0, stream>>>(A8, Qf, y, Pt, Pe, Ps);  // 988 blocks
    reduce_rows<<<16, 256, 0, stream>>>(Pt, Pe, Ps, out);
}

// Round 24
// 95.942 us; speedup vs baseline: 2.2335x; 2.2335x over previous
//
#include <hip/hip_runtime.h>
#include <hip/hip_bf16.h>
#include <stdint.h>

// ---- problem constants ----
#define NCLS   19
#define CACHE  5000
#define NTILE  313            // 16-col tiles per class (313*16 = 5008, 8 pad cols)
#define DDIM   256
#define NANCH  102
#define NVIEW  10
#define NROWS  1020
#define NSUB   13             // column sub-chunks per class
#define NCHUNK (NCLS*NSUB)    // 247
#define NWG    (4*NCHUNK)     // 988 pass1 blocks
#define SCALE_A 20.6099319733f   // (1/0.07) * log2(e): MFMA acc = s * log2(e)
#define LN2     0.69314718056f

using f32x4 = __attribute__((ext_vector_type(4))) float;
typedef long fp8x8;   // 8 packed OCP e4m3 bytes = one i64 MFMA operand (2 VGPRs)

#if __has_builtin(__builtin_amdgcn_exp2f)
#define EXP2(x) __builtin_amdgcn_exp2f(x)
#else
#define EXP2(x) __expf((x) * LN2)
#endif

// pack 4 f32 -> 4 OCP e4m3 bytes (gfx950: cvt_pk_fp8 emits OCP, not fnuz)
static __device__ __forceinline__ unsigned cvt4(float a, float b, float c, float d) {
    int w = 0;
    w = __builtin_amdgcn_cvt_pk_fp8_f32(a, b, w, false);   // bytes 0,1
    w = __builtin_amdgcn_cvt_pk_fp8_f32(c, d, w, true);    // bytes 2,3
    return (unsigned)w;
}

// Raw barrier WITHOUT the vmcnt(0) drain __syncthreads emits (m97/m233).
#define BARRIER_NODRAIN() do {                                   \
        asm volatile("s_waitcnt lgkmcnt(0)" ::: "memory");       \
        __builtin_amdgcn_sched_barrier(0);                       \
        __builtin_amdgcn_s_barrier();                            \
        __builtin_amdgcn_sched_barrier(0);                       \
    } while (0)

// ---- anchors: view-major [1024][256] fp8, pre-scaled by (1/T)*log2(e) ----
__global__ __launch_bounds__(64) void conv_anchor_fp8(const float* __restrict__ X,
                                                      unsigned* __restrict__ A8) {
    int n = blockIdx.x;     // 0..1023
    int k = threadIdx.x;    // 0..63, handles f32 elems k*4..+3
    float v0 = 0.f, v1 = 0.f, v2 = 0.f, v3 = 0.f;
    if (n < NROWS) {
        int vv = n / NANCH, a = n - vv * NANCH;
        f32x4 u = *reinterpret_cast<const f32x4*>(
            X + ((size_t)a * NVIEW + vv) * DDIM + k * 4);
        v0 = u[0] * SCALE_A; v1 = u[1] * SCALE_A;
        v2 = u[2] * SCALE_A; v3 = u[3] * SCALE_A;
    }
    A8[(size_t)n * 64 + k] = cvt4(v0, v1, v2, v3);
}

// ---- fused pass: fp8 pipeline + kk-XOR LDS swizzle (session optimum, R22) ----
// mfma_f32_16x16x32_fp8_fp8 (same rate as bf16, half the operand regs):
// afrag 64 VGPRs, live set ~100 -> 3 waves/SIMD via launch_bounds(256,3).
// (256,4) spills: unified file splits 128/wave across VGPR+AGPR (R23).
// LDS XOR swizzle (kk<<4) on BOTH write and read: staging writes spread to
// 16 slots x 4 lanes (minimal phases); conflicts 11.4M -> 761K (R22).
// Distance-2 register prefetch covers HBM latency (R16, +7%).
__global__ __launch_bounds__(256, 3) void pass1_kernel(
    const unsigned char* __restrict__ A8, const float* __restrict__ Qf,
    const int* __restrict__ y,
    float* __restrict__ Pt, float* __restrict__ Pe, float* __restrict__ Ps)
{
    __shared__ unsigned char lds[2][4096];   // 2 x 4KB fp8 fragment tiles

    // bijective XCD swizzle (m204): nwg=988, 8 XCDs, q=123, r=4.
    int orig = blockIdx.x;
    int xcd = orig & 7, slot = orig >> 3;
    int wid = (xcd < 4 ? xcd * 124 : 496 + (xcd - 4) * 123) + slot;
    int rt = wid & 3;           // row tile (256 rows)
    int cs = wid >> 2;          // 0..246 column chunk
    int cls = cs / NSUB;
    int sub = cs - cls * NSUB;
    int t0 = (NTILE * sub) / NSUB, t1 = (NTILE * (sub + 1)) / NSUB;

    int tid = threadIdx.x;
    int wave = tid >> 6, lane = tid & 63;
    int lg = lane >> 4, lm = lane & 15;
    int wrb = rt * 256 + wave * 64;   // this wave owns rows [wrb, wrb+64)

    // stage-thread mapping (R10): col c = tid>>4, 64B f32 segment seg = tid&15
    int c   = tid >> 4;
    int seg = tid & 15;
    unsigned wa0 = ((unsigned)(seg * 256 + c * 8)) ^ ((unsigned)((seg >> 1) << 4));
    const float* qbase = Qf + (size_t)cls * CACHE * DDIM + seg * 16;

    // A fragments (fp8, log2-scaled): frag f rows wrb+f*16, row = lane&15,
    // k = kk*32 + lg*8 + j  ->  8 bytes at row*256 + kk*32 + lg*8
    fp8x8 afrag[4][8];
    #pragma unroll
    for (int f = 0; f < 4; ++f)
        #pragma unroll
        for (int kk = 0; kk < 8; ++kk)
            afrag[f][kk] = *reinterpret_cast<const long*>(
                A8 + (size_t)(wrb + f * 16 + lm) * DDIM + kk * 32 + lg * 8);

    float tacc[4][4] = {}, sacc[4][4] = {};

    // two named staging reg sets (distance-2 prefetch)
    f32x4 sA0, sA1, sA2, sA3, sB0, sB1, sB2, sB3;
    bool okA, okB;

#define SLOAD1(R0, R1, R2, R3, OK, t) do {                                    \
        int _col = (t) * 16 + c;                                              \
        OK = _col < CACHE;                                                    \
        const f32x4* _src = reinterpret_cast<const f32x4*>(                   \
            qbase + (size_t)(OK ? _col : CACHE - 1) * DDIM);                  \
        R0 = _src[0]; R1 = _src[1]; R2 = _src[2]; R3 = _src[3];               \
    } while (0)

#define CVTW1(R0, R1, R2, R3, OK, buf) do {                                   \
        unsigned _w0 = cvt4(R0[0], R0[1], R0[2], R0[3]);                      \
        unsigned _w1 = cvt4(R1[0], R1[1], R1[2], R1[3]);                      \
        unsigned _w2 = cvt4(R2[0], R2[1], R2[2], R2[3]);                      \
        unsigned _w3 = cvt4(R3[0], R3[1], R3[2], R3[3]);                      \
        unsigned long long _lo = (unsigned long long)_w0 |                    \
                                 ((unsigned long long)_w1 << 32);             \
        unsigned long long _hi = (unsigned long long)_w2 |                    \
                                 ((unsigned long long)_w3 << 32);             \
        if (!OK) { _lo = 0ull; _hi = 0ull; }                                  \
        *reinterpret_cast<unsigned long long*>(&lds[buf][wa0])       = _lo;   \
        *reinterpret_cast<unsigned long long*>(&lds[buf][wa0 + 128]) = _hi;   \
    } while (0)

#define COMPUTE(buf) do {                                                     \
        fp8x8 bfrag[8];                                                       \
        _Pragma("unroll")                                                     \
        for (int kk = 0; kk < 8; ++kk)                                        \
            bfrag[kk] = *reinterpret_cast<const long*>(                       \
                &lds[buf][(unsigned)((kk * 64 + lane) * 8) ^                  \
                          (unsigned)(kk << 4)]);                              \
        f32x4 acc[4];                                                         \
        _Pragma("unroll")                                                     \
        for (int f = 0; f < 4; ++f) acc[f] = (f32x4){0.f, 0.f, 0.f, 0.f};     \
        _Pragma("unroll")                                                     \
        for (int kk = 0; kk < 8; ++kk)                                        \
            _Pragma("unroll")                                                 \
            for (int f = 0; f < 4; ++f)                                       \
                acc[f] = __builtin_amdgcn_mfma_f32_16x16x32_fp8_fp8(          \
                    afrag[f][kk], bfrag[kk], acc[f], 0, 0, 0);                \
        _Pragma("unroll")                                                     \
        for (int f = 0; f < 4; ++f)                                           \
            _Pragma("unroll")                                                 \
            for (int r = 0; r < 4; ++r) {                                     \
                float v = acc[f][r];            /* s * log2(e) */             \
                tacc[f][r] += EXP2(v);          /* pad cols: v=0 -> e=1 */    \
                sacc[f][r] += v;                                              \
            }                                                                 \
    } while (0)

#define SLOADA(t) SLOAD1(sA0, sA1, sA2, sA3, okA, t)
#define SLOADB(t) SLOAD1(sB0, sB1, sB2, sB3, okB, t)
#define CVTWRITEA(buf) CVTW1(sA0, sA1, sA2, sA3, okA, buf)
#define CVTWRITEB(buf) CVTW1(sB0, sB1, sB2, sB3, okB, buf)

    int nt = t1 - t0;

    // prologue: window 0 staged via A; window 1 preloaded into B
    SLOADA(t0);
    CVTWRITEA(0);
    if (nt > 1) SLOADB(t0 + 1);
    BARRIER_NODRAIN();

    int cur = 0, it = 0;
    for (;;) {
        if (it + 2 < nt) SLOADA(t0 + it + 2);
        COMPUTE(cur);
        if (it + 1 < nt) CVTWRITEB(cur ^ 1);
        BARRIER_NODRAIN();
        cur ^= 1; ++it;
        if (it >= nt) break;

        if (it + 2 < nt) SLOADB(t0 + it + 2);
        COMPUTE(cur);
        if (it + 1 < nt) CVTWRITEA(cur ^ 1);
        BARRIER_NODRAIN();
        cur ^= 1; ++it;
        if (it >= nt) break;
    }
#undef SLOAD1
#undef CVTW1
#undef COMPUTE
#undef SLOADA
#undef SLOADB
#undef CVTWRITEA
#undef CVTWRITEB

    // reduce across the 16 column-lanes (lm) and store per-chunk partials
    #pragma unroll
    for (int f = 0; f < 4; ++f)
        #pragma unroll
        for (int r = 0; r < 4; ++r) {
            float t = tacc[f][r], s = sacc[f][r];
            #pragma unroll
            for (int m = 1; m < 16; m <<= 1) {
                t += __shfl_xor(t, m);
                s += __shfl_xor(s, m);
            }
            if (lm == 0) {
                int row = wrb + f * 16 + lg * 4 + r;
                float mp = (row < NROWS && y[row % NANCH] == cls) ? 1.0f : 0.0f;
                size_t idx = (size_t)cs * 1024 + row;
                Pt[idx] = t; Pe[idx] = mp * t; Ps[idx] = mp * s;
            }
        }
}

// ---- per-row finalization + final mean, fused ----
__global__ __launch_bounds__(256) void reduce_rows(const float* __restrict__ Pt,
                                                   const float* __restrict__ Pe,
                                                   const float* __restrict__ Ps,
                                                   float* __restrict__ out) {
    int tid = threadIdx.x;
    int row = blockIdx.x * 64 + (tid >> 2);   // 0..1023
    int part = tid & 3;
    float tot = 0.f, pe = 0.f, ps = 0.f;
    for (int c = part; c < NCHUNK; c += 4) {
        size_t idx = (size_t)c * 1024 + row;
        tot += Pt[idx]; pe += Pe[idx]; ps += Ps[idx];
    }
    tot += __shfl_xor(tot, 1); pe += __shfl_xor(pe, 1); ps += __shfl_xor(ps, 1);
    tot += __shfl_xor(tot, 2); pe += __shfl_xor(pe, 2); ps += __shfl_xor(ps, 2);
    float contrib = 0.f;
    if (part == 0 && row < NROWS) {
        // tot includes all 19*8=152 pad cols (e=1 each); pe the 8 pads of pos class
        float ns    = tot - pe - 144.0f;        // sum exp over true negatives
        float pos_e = pe - 8.0f;                // sum exp over true positives
        float pos_s = ps * LN2;                 // sum of s over positives (ln domain)
        // sum_pos log(e^s + ns) ~= 5000*log(ns) + pos_e/ns   (first-order log1p)
        float sum_logprob = pos_s - (5000.0f * logf(ns) + pos_e / ns);
        contrib = -sum_logprob / (5000.0f + 1e-4f);
    }
    #pragma unroll
    for (int m = 1; m < 64; m <<= 1) contrib += __shfl_xor(contrib, m);
    __shared__ float sb[4];
    if ((tid & 63) == 0) sb[tid >> 6] = contrib;
    __syncthreads();
    if (tid == 0)
        atomicAdd(out, (sb[0] + sb[1] + sb[2] + sb[3]) * (1.0f / (float)NROWS));
}

extern "C" void kernel_launch(void* const* d_in, const int* in_sizes, int n_in,
                              void* d_out, int out_size, void* d_ws, size_t ws_size,
                              hipStream_t stream) {
    const float* X  = (const float*)d_in[0];   // [102][10][256]
    const int*   y  = (const int*)d_in[1];     // [102]
    const float* Qf = (const float*)d_in[2];   // [19][5000][256]
    float* out = (float*)d_out;

    char* ws = (char*)d_ws;
    // ws layout (bytes):
    //   A8  [1024][256] fp8            :    262,144
    //   Pt  [247][1024] f32            :  1,011,712
    //   Pe  [247][1024] f32            :  1,011,712
    //   Ps  [247][1024] f32            :  1,011,712
    unsigned char* A8 = (unsigned char*)(ws);
    float* Pt = (float*)(ws + 262144);
    float* Pe = (float*)(ws + 1273856);
    float* Ps = (float*)(ws + 2285568);

    hipMemsetAsync(out, 0, sizeof(float) * (size_t)out_size, stream);
    conv_anchor_fp8<<<1024, 64, 0, stream>>>(X, (unsigned*)A8);
    pass1_kernel<<<NWG, 256, 0, stream>>>(A8, Qf, y, Pt, Pe, Ps);  // 988 blocks
    reduce_rows<<<16, 256, 0, stream>>>(Pt, Pe, Ps, out);
}